// Round 16
// baseline (41.757 us; speedup 1.0000x reference)
//
#include <hip/hip_runtime.h>
#include <hip/hip_bf16.h>
#include <math.h>

#define IN_C 31
#define OUT_C 31
#define NPIX 16384
#define UW_OFF 7688
#define RW_OFF 8649
#define PART_OFF (640 * 1024)  // ws: 31 chunks (620 KB) + 20 KB pad, then partials
#define CHUNK_BYTES 20480      // 20 KB of packed B-fragments per input channel i

typedef __attribute__((ext_vector_type(8))) _Float16 f16x8;
typedef __attribute__((ext_vector_type(4))) float f32x4;

__device__ inline short f2h(float f) {            // prep kernel only (cold): RNE
    union { _Float16 h; short s; } cv;
    cv.h = (_Float16)f;
    return cv.s;
}

// ---------------- prep: pack generator weights into MFMA B-fragment chunks ----
// ws layout: for i in [0,31): 20 chunks of 1 KB (20 KB per i, 620 KB total):
//   pairs 0..7 : spline B, chunk = kc*2 + nt  (kc in [0,8), nt in {0,1})
//   pair 8 (chunks 16,17) : uw B;  pair 9 (chunks 18,19) : rw B   (FP16)
__global__ __launch_bounds__(64) void kan_prep_kernel(
    const float* __restrict__ gw, const float* __restrict__ gb,
    unsigned short* __restrict__ ws)
{
    const int blk = blockIdx.x;          // 31*20 = 620
    const int i   = blk / 20;
    const int ch  = blk % 20;
    const int l   = threadIdx.x;
    const int col = l & 15;
    const int krow = l >> 4;
    const int o = (ch & 1) * 16 + col;

    int p;
    if (ch < 16)      p = (i * 31 + o) * 8 + (ch >> 1);
    else if (ch < 18) p = UW_OFF + i * 31 + o;
    else              p = RW_OFF + i * 31 + o;

    short v8[8];
#pragma unroll
    for (int j = 0; j < 8; ++j) {
        const int c = krow * 8 + j;
        float v = 0.f;
        if (o < OUT_C) v = (c < IN_C) ? gw[p * 31 + c] : gb[p];
        v8[j] = f2h(v);
    }
    *(f16x8*)&ws[(blk * 64 + l) * 8] = *(f16x8*)v8;
}

// Stage one i-PAIR (2 adjacent chunks = 40 KB, contiguous in ws) into LDS via
// async DMA: 2560 16B slots, 512 threads x 5 slots. The phantom chunk past
// i=30 reads the 20 KB pad below PART_OFF (valid memory, values unused).
__device__ __forceinline__ void stage_pair(const unsigned char* wsrc,
                                           unsigned char* ldst, int t) {
#pragma unroll
    for (int k = 0; k < 5; ++k) {
        const int off = (k * 512 + t) * 16;
        __builtin_amdgcn_global_load_lds(
            (const __attribute__((address_space(1))) unsigned int*)(wsrc + off),
            (__attribute__((address_space(3))) unsigned int*)(ldst + off),
            16, 0, 0);
    }
}

// ---------------- main: 32 px/wave (LDS economy) x 2 i-streams (ILP) ----------
// Block = 512 thr = 8 waves x 32 px (2 M-tiles) = 256 px; waves share the SAME
// i-pair. Spline phase runs BOTH streams interleaved (independent SPA/SPB
// chains = R15's proven ILP win); uw/rw phases run per-stream with an
// immediately-folded zero-C UW temp (keeps peak VGPR ~100, under the 128
// cliff). B-fragments are shared across both M-tiles (R12's LDS economy:
// 640 B/px/i, half of R15's). One 40 KB pair-stage DMA + ONE barrier per 2 i.
// LDS = 2x40 KB = 80 KB -> 2 blocks/CU. gridDim.y=8 -> 512 blocks = 2/CU.
__global__ __launch_bounds__(512) void kan_mfma12_kernel(
    const float* __restrict__ x,               // (31, 16384)
    const unsigned char* __restrict__ wsw,     // packed B fragments (bytes)
    float* __restrict__ parts,                 // (nsplit-1) x (31,16384)
    float* __restrict__ out,                   // (31, 16384)
    int nsplit)
{
    const int t = threadIdx.x;
    const int l = t & 63;
    const int w = t >> 6;                      // 0..7
    const int pix0 = blockIdx.x * 256;
    const int csize = (IN_C + nsplit - 1) / nsplit;
    const int ibase = blockIdx.y * csize;
    const int iend = min(ibase + csize, IN_C);

    __shared__ __align__(16) unsigned char bufs[2][2 * CHUNK_BYTES]; // 80 KB

    const int n0 = w * 32;

    // x~ fragments (f16, once per block), both M-tiles.
    f16x8 xv8f[2];
#pragma unroll
    for (int mt = 0; mt < 2; ++mt) {
        const int row = pix0 + n0 + mt * 16 + (l & 15);
        const int cb = (l >> 4) * 8;
#pragma unroll
        for (int j = 0; j < 8; ++j) {
            const int c = cb + j;
            const float v = (c < IN_C) ? x[c * NPIX + row] : 1.0f;  // x~[31]=1
            xv8f[mt][j] = (_Float16)v;
        }
    }

    f32x4 Y[2][2];
#pragma unroll
    for (int mt = 0; mt < 2; ++mt)
#pragma unroll
        for (int nt = 0; nt < 2; ++nt) Y[mt][nt] = (f32x4){0.f, 0.f, 0.f, 0.f};

    // prologue: stage first pair
    stage_pair(wsw + (size_t)ibase * CHUNK_BYTES, bufs[0], t);
    __syncthreads();

    const int npairs = (iend - ibase + 1) >> 1;

#pragma unroll 1
    for (int tp = 0; tp < npairs; ++tp) {
        const int i0 = ibase + 2 * tp;
        const bool has1 = (i0 + 1) < iend;     // wave-uniform

        // stage next pair into the other buffer (in flight across compute)
        if (tp + 1 < npairs)
            stage_pair(wsw + (size_t)(i0 + 2) * CHUNK_BYTES, bufs[(tp + 1) & 1], t);

        // per-i x values for both M-tiles (L2 hits; overlap basis below)
        const int pr0 = pix0 + n0 + (l & 15);
        const float xa0 = x[i0 * NPIX + pr0];
        const float xa1 = x[i0 * NPIX + pr0 + 16];
        const float xb0 = has1 ? x[(i0 + 1) * NPIX + pr0] : 0.f;
        const float xb1 = has1 ? x[(i0 + 1) * NPIX + pr0 + 16] : 0.f;

        // basis + silu for both streams x both M-tiles
        _Float16 basA[2][8], basB[2][8];
        float silA[2], silB[2];
#pragma unroll
        for (int s = 0; s < 4; ++s) {          // s = stream*2 + mt
            const float xv = (s == 0) ? xa0 : (s == 1) ? xa1
                           : (s == 2) ? xb0 : xb1;
            const float tb = (xv + 2.2f) * 2.5f;
            const float jf = floorf(tb);
            const float u  = tb - jf;
            const int  jj  = (int)jf;
            const float u2 = u * u, u3 = u2 * u;
            const float b0v = u3 * (1.f / 6.f);
            const float b1v = (-3.f * u3 + 3.f * u2 + 3.f * u + 1.f) * (1.f / 6.f);
            const float b2v = (3.f * u3 - 6.f * u2 + 4.f) * (1.f / 6.f);
            const float omu = 1.f - u;
            const float b3v = omu * omu * omu * (1.f / 6.f);
#pragma unroll
            for (int m = 0; m < 8; ++m) {
                const int d = jj - m;
                const float bv = (d == 0) ? b0v : (d == 1) ? b1v : (d == 2) ? b2v
                               : (d == 3) ? b3v : 0.f;
                if (s < 2) basA[s][m] = (_Float16)bv;
                else       basB[s - 2][m] = (_Float16)bv;
            }
            const float sv = xv / (1.f + __expf(-xv));
            if (s < 2) silA[s] = sv; else silB[s - 2] = sv;
        }

        const unsigned char* wbA = bufs[tp & 1];
        const unsigned char* wbB = wbA + CHUNK_BYTES;

        f32x4 SPA[2][2], SPB[2][2];
#pragma unroll
        for (int mt = 0; mt < 2; ++mt)
#pragma unroll
            for (int nt = 0; nt < 2; ++nt) {
                SPA[mt][nt] = (f32x4){0.f, 0.f, 0.f, 0.f};
                SPB[mt][nt] = (f32x4){0.f, 0.f, 0.f, 0.f};
            }

        // ---- spline: 8 kc, BOTH streams interleaved (independent chains) ----
#pragma unroll
        for (int p = 0; p < 8; ++p) {
            const f16x8 a0 = *(const f16x8*)(wbA + ((p * 2 + 0) * 64 + l) * 16);
            const f16x8 a1 = *(const f16x8*)(wbA + ((p * 2 + 1) * 64 + l) * 16);
#pragma unroll
            for (int mt = 0; mt < 2; ++mt) {
                const f16x8 afA = xv8f[mt] * basA[mt][p];
                SPA[mt][0] = __builtin_amdgcn_mfma_f32_16x16x32_f16(afA, a0, SPA[mt][0], 0, 0, 0);
                SPA[mt][1] = __builtin_amdgcn_mfma_f32_16x16x32_f16(afA, a1, SPA[mt][1], 0, 0, 0);
            }
            if (has1) {
                const f16x8 c0 = *(const f16x8*)(wbB + ((p * 2 + 0) * 64 + l) * 16);
                const f16x8 c1 = *(const f16x8*)(wbB + ((p * 2 + 1) * 64 + l) * 16);
#pragma unroll
                for (int mt = 0; mt < 2; ++mt) {
                    const f16x8 afB = xv8f[mt] * basB[mt][p];
                    SPB[mt][0] = __builtin_amdgcn_mfma_f32_16x16x32_f16(afB, c0, SPB[mt][0], 0, 0, 0);
                    SPB[mt][1] = __builtin_amdgcn_mfma_f32_16x16x32_f16(afB, c1, SPB[mt][1], 0, 0, 0);
                }
            }
        }

        // ---- uw + fold, then rw, per stream (temporal: short UW live range) --
        {
            const f16x8 u0 = *(const f16x8*)(wbA + (16 * 64 + l) * 16);
            const f16x8 u1 = *(const f16x8*)(wbA + (17 * 64 + l) * 16);
            const f32x4 z = (f32x4){0.f, 0.f, 0.f, 0.f};
#pragma unroll
            for (int mt = 0; mt < 2; ++mt) {
                const f32x4 uw0 = __builtin_amdgcn_mfma_f32_16x16x32_f16(xv8f[mt], u0, z, 0, 0, 0);
                const f32x4 uw1 = __builtin_amdgcn_mfma_f32_16x16x32_f16(xv8f[mt], u1, z, 0, 0, 0);
#pragma unroll
                for (int r = 0; r < 4; ++r) {
                    Y[mt][0][r] = fmaf(uw0[r], SPA[mt][0][r], Y[mt][0][r]);
                    Y[mt][1][r] = fmaf(uw1[r], SPA[mt][1][r], Y[mt][1][r]);
                }
            }
            const f16x8 r0 = *(const f16x8*)(wbA + (18 * 64 + l) * 16);
            const f16x8 r1 = *(const f16x8*)(wbA + (19 * 64 + l) * 16);
#pragma unroll
            for (int mt = 0; mt < 2; ++mt) {
                const f16x8 arw = xv8f[mt] * (_Float16)silA[mt];
                Y[mt][0] = __builtin_amdgcn_mfma_f32_16x16x32_f16(arw, r0, Y[mt][0], 0, 0, 0);
                Y[mt][1] = __builtin_amdgcn_mfma_f32_16x16x32_f16(arw, r1, Y[mt][1], 0, 0, 0);
            }
        }
        if (has1) {
            const f16x8 u0 = *(const f16x8*)(wbB + (16 * 64 + l) * 16);
            const f16x8 u1 = *(const f16x8*)(wbB + (17 * 64 + l) * 16);
            const f32x4 z = (f32x4){0.f, 0.f, 0.f, 0.f};
#pragma unroll
            for (int mt = 0; mt < 2; ++mt) {
                const f32x4 uw0 = __builtin_amdgcn_mfma_f32_16x16x32_f16(xv8f[mt], u0, z, 0, 0, 0);
                const f32x4 uw1 = __builtin_amdgcn_mfma_f32_16x16x32_f16(xv8f[mt], u1, z, 0, 0, 0);
#pragma unroll
                for (int r = 0; r < 4; ++r) {
                    Y[mt][0][r] = fmaf(uw0[r], SPB[mt][0][r], Y[mt][0][r]);
                    Y[mt][1][r] = fmaf(uw1[r], SPB[mt][1][r], Y[mt][1][r]);
                }
            }
            const f16x8 r0 = *(const f16x8*)(wbB + (18 * 64 + l) * 16);
            const f16x8 r1 = *(const f16x8*)(wbB + (19 * 64 + l) * 16);
#pragma unroll
            for (int mt = 0; mt < 2; ++mt) {
                const f16x8 arw = xv8f[mt] * (_Float16)silB[mt];
                Y[mt][0] = __builtin_amdgcn_mfma_f32_16x16x32_f16(arw, r0, Y[mt][0], 0, 0, 0);
                Y[mt][1] = __builtin_amdgcn_mfma_f32_16x16x32_f16(arw, r1, Y[mt][1], 0, 0, 0);
            }
        }

        // ONE barrier per pair: drains vmcnt (next pair staged) + ordering
        __syncthreads();
    }

    // ---- gather Y into bufs (free now) for coalesced store ----
    float* yb = (float*)bufs;   // 256*33 floats = 33.8 KB << 80 KB
#pragma unroll
    for (int mt = 0; mt < 2; ++mt)
#pragma unroll
        for (int nt = 0; nt < 2; ++nt)
#pragma unroll
            for (int r = 0; r < 4; ++r) {
                const int p = n0 + mt * 16 + (l >> 4) * 4 + r;
                const int o = nt * 16 + (l & 15);
                if (o < OUT_C) yb[p * 33 + o] = Y[mt][nt][r];
            }
    __syncthreads();

    float* dst = (blockIdx.y == 0) ? out
               : (parts + (size_t)(blockIdx.y - 1) * OUT_C * NPIX);
    for (int idx = t; idx < 256 * OUT_C; idx += 512) {
        const int n = idx & 255, o = idx >> 8;
        dst[o * NPIX + pix0 + n] = yb[n * 33 + o];
    }
}

// ---------------- combine: out += sum of npart partials (vectorized) ----------
__global__ __launch_bounds__(256) void kan_combine_kernel(
    float* __restrict__ out, const float* __restrict__ parts, int npart)
{
    const int e = blockIdx.x * 256 + threadIdx.x;   // float4 index
    const int nv = (OUT_C * NPIX) / 4;
    if (e < nv) {
        f32x4 a = ((const f32x4*)out)[e];
        for (int j = 0; j < npart; ++j)
            a += ((const f32x4*)parts)[e + (size_t)j * nv];
        ((f32x4*)out)[e] = a;
    }
}

extern "C" void kernel_launch(void* const* d_in, const int* in_sizes, int n_in,
                              void* d_out, int out_size, void* d_ws, size_t ws_size,
                              hipStream_t stream) {
    const float* x  = (const float*)d_in[0];
    const float* gw = (const float*)d_in[1];
    const float* gb = (const float*)d_in[2];
    float* out = (float*)d_out;
    unsigned short* ws = (unsigned short*)d_ws;
    float* parts = (float*)((char*)d_ws + PART_OFF);

    // 8-way i-split: 7 f32 partials (14.3 MB). Deterministic fallback.
    const size_t part_bytes = (size_t)OUT_C * NPIX * 4;
    int nsplit = 8;
    if (ws_size < PART_OFF + 7 * part_bytes) nsplit = 4;
    if (ws_size < PART_OFF + 3 * part_bytes) nsplit = 2;

    hipLaunchKernelGGL(kan_prep_kernel, dim3(620), dim3(64), 0, stream, gw, gb, ws);
    hipLaunchKernelGGL(kan_mfma12_kernel, dim3(NPIX / 256, nsplit), dim3(512), 0, stream,
                       x, (const unsigned char*)d_ws, parts, out, nsplit);
    const int nv = (OUT_C * NPIX) / 4;                 // 126976
    hipLaunchKernelGGL(kan_combine_kernel, dim3((nv + 255) / 256), dim3(256), 0, stream,
                       out, parts, nsplit - 1);
}